// Round 12
// baseline (139.077 us; speedup 1.0000x reference)
//
#include <hip/hip_runtime.h>
#include <hip/hip_bf16.h>

#define NN 9216
#define CC 256
#define LOG2E 1.4426950408889634f

typedef __attribute__((ext_vector_type(8))) short short8;
typedef __attribute__((ext_vector_type(16))) float floatx16;
typedef __attribute__((ext_vector_type(4))) float floatx4;
typedef __attribute__((ext_vector_type(4))) unsigned short ushortx4;

#if __has_builtin(__builtin_amdgcn_exp2f)
#define fexp2 __builtin_amdgcn_exp2f
#else
#define fexp2 exp2f
#endif

__device__ __forceinline__ unsigned short f2bf(float f) {
    unsigned u = __float_as_uint(f);
    u = u + 0x7fffu + ((u >> 16) & 1u);
    return (unsigned short)(u >> 16);
}
__device__ __forceinline__ float bf2f(unsigned short s) {
    return __uint_as_float(((unsigned)s) << 16);
}
__device__ __forceinline__ unsigned pack2bf(float a, float b) {
    union { __hip_bfloat162 h; unsigned u; } cv;
    cv.h = __float22bfloat162_rn(make_float2(a, b));
    return cv.u;
}
__device__ __forceinline__ floatx16 mfma_bf16(short8 a, short8 b, floatx16 c) {
    return __builtin_amdgcn_mfma_f32_32x32x16_bf16(a, b, c, 0, 0, 0);
}

// K0: transpose+hi/lo-split inputs into B-fragment order XB/EB[nt][kb][lane][8].
__global__ __launch_bounds__(256) void prep(
    const float* __restrict__ x, const float* __restrict__ xe,
    short* __restrict__ XBhi, short* __restrict__ XBlo,
    short* __restrict__ EBhi, short* __restrict__ EBlo)
{
    int t = threadIdx.x;
    const float* in = blockIdx.y ? xe : x;
    short* Dhi = blockIdx.y ? EBhi : XBhi;
    short* Dlo = blockIdx.y ? EBlo : XBlo;
    int tl = t & 31, sub = t >> 5;
    int nt = blockIdx.x >> 2, q4 = blockIdx.x & 3;
    int sub2 = q4 * 8 + sub;            // 0..31
    int kb_ = sub2 >> 1, hl = sub2 & 1;
    int n = nt * 32 + tl;
    int c0 = kb_ * 16 + hl * 8;
    union { unsigned short us[8]; short8 v8; } hi, lo;
#pragma unroll
    for (int j = 0; j < 8; ++j) {
        float val = in[(size_t)(c0 + j) * NN + n];
        unsigned short hb = f2bf(val);
        hi.us[j] = hb;
        lo.us[j] = f2bf(val - bf2f(hb));
    }
    size_t off = (((size_t)nt * 16 + kb_) * 64 + hl * 32 + tl) * 8;
    *(short8*)(Dhi + off) = hi.v8;
    *(short8*)(Dlo + off) = lo.v8;
}

// K0b: weights -> A-fragment order WA[ot][kb][lane][8], hi/lo split.
__global__ __launch_bounds__(256) void wprep(
    const float* __restrict__ qw, const float* __restrict__ kw,
    const float* __restrict__ vw,
    short* __restrict__ WAhi, short* __restrict__ WAlo)
{
    int g = blockIdx.x * 256 + threadIdx.x;     // 0..10239
    int lane = g & 63, kb_ = (g >> 6) & 15, ot = g >> 10;
    int o = lane & 31, half = lane >> 5;
    int c0 = kb_ * 16 + half * 8;
    const float* wsrc;
    int orow;
    float scale = 1.f;
    if (ot == 0) { wsrc = qw; orow = o; scale = LOG2E; }
    else if (ot == 1) { wsrc = kw; orow = o; }
    else { wsrc = vw; orow = (ot - 2) * 32 + o; }
    union { unsigned short us[8]; short8 v8; } hi, lo;
#pragma unroll
    for (int j = 0; j < 8; ++j) {
        float val = wsrc[(size_t)orow * 256 + c0 + j] * scale;
        unsigned short hb = f2bf(val);
        hi.us[j] = hb;
        lo.us[j] = f2bf(val - bf2f(hb));
    }
    size_t off = (((size_t)ot * 16 + kb_) * 64 + lane) * 8;
    *(short8*)(WAhi + off) = hi.v8;
    *(short8*)(WAlo + off) = lo.v8;
}

// K1: all projections via MFMA (see round-2 notes). grid (144, 5), 256 thr.
__global__ __launch_bounds__(256) void gemm_all(
    const short* __restrict__ XBhi, const short* __restrict__ XBlo,
    const short* __restrict__ EBhi, const short* __restrict__ EBlo,
    const short* __restrict__ WAhi, const short* __restrict__ WAlo,
    const float* __restrict__ qb, const float* __restrict__ kb,
    const float* __restrict__ hpos, const float* __restrict__ wpos,
    const float* __restrict__ vb,
    short* __restrict__ Qhi, short* __restrict__ Qlo,
    short* __restrict__ KP2, short* __restrict__ VF)
{
    __shared__ float lds[4][1024];
    int t = threadIdx.x;
    int wv = t >> 6, lane = t & 63, ln = lane & 31, h = lane >> 5;
    int nt = blockIdx.x * 2 + (wv & 1);
    int tile = blockIdx.y * 2 + (wv >> 1);

    const short* Bhi = (tile == 0 ? XBhi : EBhi) + (size_t)nt * 8192 + lane * 8;
    const short* Blo = (tile == 0 ? XBlo : EBlo) + (size_t)nt * 8192 + lane * 8;
    const short* Ahi = WAhi + (size_t)tile * 8192 + lane * 8;
    const short* Alo = WAlo + (size_t)tile * 8192 + lane * 8;

    floatx16 D;
#pragma unroll
    for (int r = 0; r < 16; ++r) D[r] = 0.f;
#pragma unroll
    for (int k = 0; k < 16; ++k) {
        short8 bh = *(const short8*)(Bhi + k * 512);
        short8 bl = *(const short8*)(Blo + k * 512);
        short8 ah = *(const short8*)(Ahi + k * 512);
        short8 al = *(const short8*)(Alo + k * 512);
        D = mfma_bf16(ah, bh, D);
        D = mfma_bf16(ah, bl, D);
        D = mfma_bf16(al, bh, D);
    }

    float* L = lds[wv];
#pragma unroll
    for (int r = 0; r < 16; ++r) {
        int row = (r & 3) + 8 * (r >> 2) + 4 * h;
        L[row * 32 + ((ln + row) & 31)] = D[r];     // (col+row)&31 bank swizzle
    }
    __syncthreads();

    if (tile == 0) {
        int n = nt * 32 + ln;
#pragma unroll
        for (int it = 0; it < 2; ++it) {
            int j0 = it * 16 + h * 8;
            union { unsigned short us[8]; short8 v8; } qh_, ql_;
#pragma unroll
            for (int jj = 0; jj < 8; ++jj) {
                int row = j0 + jj;
                float d = L[row * 32 + ((ln + row) & 31)] + qb[row] * LOG2E;
                unsigned short hb = f2bf(d);
                qh_.us[jj] = hb;
                ql_.us[jj] = f2bf(d - bf2f(hb));
            }
            *(short8*)(Qhi + (size_t)n * 32 + j0) = qh_.v8;
            *(short8*)(Qlo + (size_t)n * 32 + j0) = ql_.v8;
        }
    } else if (tile == 1) {
        int n = nt * 32 + ln;
        int hh = ((n >> 5) * 683) >> 11;     // n/96
        int ww = n - hh * 96;
#pragma unroll
        for (int it = 0; it < 2; ++it) {
            int jb0 = it * 16 + h * 8;
            union { unsigned short us[8]; short8 v8; } o;
#pragma unroll
            for (int jj = 0; jj < 8; ++jj) {
                int row = jb0 + jj;
                float d = L[row * 32 + ((ln + row) & 31)]
                        + kb[row] + hpos[row * 96 + hh] + wpos[row * 96 + ww];
                o.us[jj] = f2bf(d);
            }
            *(short8*)(KP2 + (size_t)nt * 1024 + it * 512 + h * 256 + ln * 8) = o.v8;
        }
    } else {
        int cc = tile - 2;
        float bias = vb[cc * 32 + ln];
#pragma unroll
        for (int it = 0; it < 2; ++it) {
            union { unsigned short us[8]; short8 v8; } o;
#pragma unroll
            for (int ee = 0; ee < 8; ++ee) {
                int ml = it * 16 + h * 8 + ee;
                float d = L[ln * 32 + ((ml + ln) & 31)];
                o.us[ee] = f2bf(d + bias);
            }
            *(short8*)(VF + ((size_t)(nt * 2 + it) * 8 + cc) * 512 + lane * 8) = o.v8;
        }
    }
}

// K3: flash attention, produce/consume P-broadcast via LDS.
// Block = 256 thr = 4 waves; wave w owns c-quarter w (64 c) x 64 n. Per 128-m
// super-iteration: wave w computes QK+softmax for ONE 32-m chunk (slot w) and
// writes P to LDS in B-fragment order (layout materializes the verified
// shfl_xor select: per n, grp g = [w(2g)h0, w(2g+1)h0, w(2g)h1, w(2g+1)h1],
// row stride 72B -> 2-way-free banks); after ONE __syncthreads, every wave
// PV-consumes all 4 chunks on its c-quarter. S computed once chip-wide;
// softmax VALU spread 4x across waves; O acc halves to 64 -> ~2 waves/SIMD.
// Double-buffered P; produce targets the buffer consumed LAST iteration ->
// race-free with plain barriers. Fixed-max softmax (max=0).
#define PRODUCE(CH, BUF) do {                                                      \
    const short* kp_ = KPb + (size_t)(CH) * 1024;                                  \
    short8 ah0_ = *(const short8*)(kp_);                                           \
    short8 ah1_ = *(const short8*)(kp_ + 512);                                     \
    floatx16 SA = {0.f,0.f,0.f,0.f,0.f,0.f,0.f,0.f,0.f,0.f,0.f,0.f,0.f,0.f,0.f,0.f}; \
    SA = mfma_bf16(ah0_, qAh0, SA);                                                \
    SA = mfma_bf16(ah0_, qAl0, SA);                                                \
    SA = mfma_bf16(ah1_, qAh1, SA);                                                \
    SA = mfma_bf16(ah1_, qAl1, SA);                                                \
    floatx16 SB = {0.f,0.f,0.f,0.f,0.f,0.f,0.f,0.f,0.f,0.f,0.f,0.f,0.f,0.f,0.f,0.f}; \
    SB = mfma_bf16(ah0_, qBh0, SB);                                                \
    SB = mfma_bf16(ah0_, qBl0, SB);                                                \
    SB = mfma_bf16(ah1_, qBh1, SB);                                                \
    SB = mfma_bf16(ah1_, qBl1, SB);                                                \
    float psA = 0.f, psB = 0.f;                                                    \
    _Pragma("unroll") for (int r = 0; r < 16; ++r) { SA[r] = fexp2(SA[r]); psA += SA[r]; } \
    _Pragma("unroll") for (int r = 0; r < 16; ++r) { SB[r] = fexp2(SB[r]); psB += SB[r]; } \
    psA += __shfl_xor(psA, 32); lA += psA;                                         \
    psB += __shfl_xor(psB, 32); lB += psB;                                         \
    char* pb_ = &P_lds[BUF][w][0] + ln * 72 + 8 * h;                               \
    {   unsigned long long g0 = (unsigned long long)pack2bf(SA[0], SA[1])          \
                              | ((unsigned long long)pack2bf(SA[2], SA[3]) << 32); \
        unsigned long long g1 = (unsigned long long)pack2bf(SA[4], SA[5])          \
                              | ((unsigned long long)pack2bf(SA[6], SA[7]) << 32); \
        unsigned long long g2 = (unsigned long long)pack2bf(SA[8], SA[9])          \
                              | ((unsigned long long)pack2bf(SA[10], SA[11]) << 32); \
        unsigned long long g3 = (unsigned long long)pack2bf(SA[12], SA[13])        \
                              | ((unsigned long long)pack2bf(SA[14], SA[15]) << 32); \
        *(unsigned long long*)(pb_)      = g0;                                     \
        *(unsigned long long*)(pb_ + 16) = g1;                                     \
        *(unsigned long long*)(pb_ + 32) = g2;                                     \
        *(unsigned long long*)(pb_ + 48) = g3; }                                   \
    {   unsigned long long g0 = (unsigned long long)pack2bf(SB[0], SB[1])          \
                              | ((unsigned long long)pack2bf(SB[2], SB[3]) << 32); \
        unsigned long long g1 = (unsigned long long)pack2bf(SB[4], SB[5])          \
                              | ((unsigned long long)pack2bf(SB[6], SB[7]) << 32); \
        unsigned long long g2 = (unsigned long long)pack2bf(SB[8], SB[9])          \
                              | ((unsigned long long)pack2bf(SB[10], SB[11]) << 32); \
        unsigned long long g3 = (unsigned long long)pack2bf(SB[12], SB[13])        \
                              | ((unsigned long long)pack2bf(SB[14], SB[15]) << 32); \
        *(unsigned long long*)(pb_ + 2304)      = g0;                              \
        *(unsigned long long*)(pb_ + 2304 + 16) = g1;                              \
        *(unsigned long long*)(pb_ + 2304 + 32) = g2;                              \
        *(unsigned long long*)(pb_ + 2304 + 48) = g3; }                            \
} while (0)

#define CONSUME(SLOT, BUF, CH) do {                                                \
    const short* v_ = Vb + (size_t)(CH) * 8192;                                    \
    short8 v00 = *(const short8*)(v_);               /* ks0 ct0 */                 \
    short8 v01 = *(const short8*)(v_ + 512);         /* ks0 ct1 */                 \
    short8 v10 = *(const short8*)(v_ + 4096);        /* ks1 ct0 */                 \
    short8 v11 = *(const short8*)(v_ + 4096 + 512);  /* ks1 ct1 */                 \
    const char* pr_ = &P_lds[BUF][SLOT][0] + ln * 72 + h * 16;                     \
    short8 p0A = *(const short8*)(pr_);                                            \
    short8 p1A = *(const short8*)(pr_ + 32);                                       \
    short8 p0B = *(const short8*)(pr_ + 2304);                                     \
    short8 p1B = *(const short8*)(pr_ + 2304 + 32);                                \
    OA0 = mfma_bf16(v00, p0A, OA0); OA1 = mfma_bf16(v01, p0A, OA1);                \
    OB0 = mfma_bf16(v00, p0B, OB0); OB1 = mfma_bf16(v01, p0B, OB1);                \
    OA0 = mfma_bf16(v10, p1A, OA0); OA1 = mfma_bf16(v11, p1A, OA1);                \
    OB0 = mfma_bf16(v10, p1B, OB0); OB1 = mfma_bf16(v11, p1B, OB1);                \
} while (0)

#define OGW2(OG, CT, NS) { _Pragma("unroll") for (int r = 0; r < 16; ++r) {        \
    int row = w * 64 + (CT) * 32 + (r & 3) + 8 * (r >> 2) + 4 * h;                 \
    Opart[obase + (size_t)row * NN + n0 + (NS) * 32 + ln] = f2bf(OG[r]); } }

__global__ __launch_bounds__(256, 2) void flash(
    const short* __restrict__ Qhi, const short* __restrict__ Qlo,
    const short* __restrict__ KP2, const short* __restrict__ VF,
    unsigned short* __restrict__ Opart, float* __restrict__ Lpart,
    int mqmask, int mshift, int mlen)
{
    __shared__ char P_lds[2][4][4608];   // [buf][chunk-slot][2ns x 32n x 72B]
    __shared__ float Lsh[4][2][32];

    int t = threadIdx.x;
    int w = t >> 6;                      // wave id = c-quarter = produce slot
    int lane = t & 63, ln = lane & 31, h = lane >> 5;
    int nt = blockIdx.x >> mshift, mq = blockIdx.x & mqmask;
    int n0 = nt * 64;
    int mstart = mq * mlen;
    int nsup = mlen >> 7;                // super-iterations of 128 m

    int qoffA = (n0 + ln) * 32 + h * 8;
    int qoffB = qoffA + 1024;            // +32 n
    short8 qAh0 = *(const short8*)(Qhi + qoffA);
    short8 qAl0 = *(const short8*)(Qlo + qoffA);
    short8 qAh1 = *(const short8*)(Qhi + qoffA + 16);
    short8 qAl1 = *(const short8*)(Qlo + qoffA + 16);
    short8 qBh0 = *(const short8*)(Qhi + qoffB);
    short8 qBl0 = *(const short8*)(Qlo + qoffB);
    short8 qBh1 = *(const short8*)(Qhi + qoffB + 16);
    short8 qBl1 = *(const short8*)(Qlo + qoffB + 16);

    const short* KPb = KP2 + (size_t)mstart * 32 + lane * 8;
    // VF[mt][cc][lane][8]: per mt 4096 shorts; this wave's c-quarter cc = w*2+ct
    const short* Vb = VF + ((size_t)(mstart >> 4) + (size_t)w * 0) * 4096
                         + (size_t)(mstart >> 4) * 0   /* keep simple below */
                         ;
    Vb = VF + (size_t)(mstart >> 4) * 4096 + (size_t)(w * 2) * 512 + (size_t)lane * 8;

    floatx16 OA0, OA1, OB0, OB1;         // [ct][ns]
#pragma unroll
    for (int r = 0; r < 16; ++r) { OA0[r] = 0.f; OA1[r] = 0.f; OB0[r] = 0.f; OB1[r] = 0.f; }
    float lA = 0.f, lB = 0.f;

    PRODUCE(w, 0);                       // chunks 0..3 -> buf0
    __syncthreads();

    for (int sp = 0; sp < nsup; ++sp) {
        int buf = sp & 1;
        if (sp < nsup - 1) PRODUCE((sp + 1) * 4 + w, buf ^ 1);
        int c0_ = sp * 4;
        CONSUME(0, buf, c0_ + 0);
        CONSUME(1, buf, c0_ + 1);
        CONSUME(2, buf, c0_ + 2);
        CONSUME(3, buf, c0_ + 3);
        __syncthreads();
    }

    if (lane < 32) { Lsh[w][0][ln] = lA; Lsh[w][1][ln] = lB; }
    __syncthreads();
    if (w == 0 && lane < 32) {
        Lpart[mq * NN + n0 + ln] =
            Lsh[0][0][ln] + Lsh[1][0][ln] + Lsh[2][0][ln] + Lsh[3][0][ln];
        Lpart[mq * NN + n0 + 32 + ln] =
            Lsh[0][1][ln] + Lsh[1][1][ln] + Lsh[2][1][ln] + Lsh[3][1][ln];
    }
    size_t obase = (size_t)mq * ((size_t)CC * NN);
    OGW2(OA0, 0, 0) OGW2(OA1, 1, 0) OGW2(OB0, 0, 1) OGW2(OB1, 1, 1)
}

// K5: out[c][n] = (sum_q Opart_q[c][n]) * (gamma / sum_q L_q[n]) + x[c][n]
__global__ __launch_bounds__(256) void combine(
    const unsigned short* __restrict__ Opart, const float* __restrict__ Lpart,
    const float* __restrict__ gamma, const float* __restrict__ x,
    float* __restrict__ out, int nparts)
{
    int i = blockIdx.x * 256 + threadIdx.x;   // float4 index
    int flat = i * 4;
    int n = flat % NN;                        // 4-aligned, NN%4==0 so no row cross
    floatx4 acc = *(const floatx4*)&x[flat];
    float Ls0 = 0.f, Ls1 = 0.f, Ls2 = 0.f, Ls3 = 0.f;
    float s0 = 0.f, s1 = 0.f, s2 = 0.f, s3 = 0.f;
    for (int q = 0; q < nparts; ++q) {
        floatx4 Lq = *(const floatx4*)&Lpart[q * NN + n];
        Ls0 += Lq[0]; Ls1 += Lq[1]; Ls2 += Lq[2]; Ls3 += Lq[3];
        ushortx4 o = *(const ushortx4*)(Opart + (size_t)q * ((size_t)CC * NN) + flat);
        s0 += bf2f(o[0]); s1 += bf2f(o[1]); s2 += bf2f(o[2]); s3 += bf2f(o[3]);
    }
    float g = gamma[0];
    acc[0] += s0 * (g / Ls0);
    acc[1] += s1 * (g / Ls1);
    acc[2] += s2 * (g / Ls2);
    acc[3] += s3 * (g / Ls3);
    *(floatx4*)&out[flat] = acc;
}

extern "C" void kernel_launch(void* const* d_in, const int* in_sizes, int n_in,
                              void* d_out, int out_size, void* d_ws, size_t ws_size,
                              hipStream_t stream) {
    const float* x  = (const float*)d_in[0];
    const float* xe = (const float*)d_in[1];
    const float* qw = (const float*)d_in[2];
    const float* qb = (const float*)d_in[3];
    const float* kw = (const float*)d_in[4];
    const float* kb = (const float*)d_in[5];
    const float* vw = (const float*)d_in[6];
    const float* vb = (const float*)d_in[7];
    const float* hp = (const float*)d_in[8];
    const float* wp = (const float*)d_in[9];
    const float* gm = (const float*)d_in[10];

    char* ws = (char*)d_ws;
    short* Qhi  = (short*)(ws + 0);                 // 589824 B
    short* Qlo  = (short*)(ws + 589824);            // 589824 B
    short* KP2  = (short*)(ws + 1179648);           // 589824 B
    short* WAhi = (short*)(ws + 1769472);           // 163840 B
    short* WAlo = (short*)(ws + 1933312);           // 163840 B
    short* VF   = (short*)(ws + 2097152);           // 4718592 B, ends 6815744

    const size_t OPART_OFF = 6815744;
    const size_t PART_BYTES = (size_t)CC * NN * 2;  // 4718592 per part
    int nparts = 4, mshift = 2;
    size_t need8 = OPART_OFF + 8 * PART_BYTES + (size_t)8 * NN * 4;  // ~44.9 MB
    if (ws_size >= need8) { nparts = 8; mshift = 3; }
    unsigned short* Opart = (unsigned short*)(ws + OPART_OFF);
    float* Lpart = (float*)(ws + OPART_OFF + (size_t)nparts * PART_BYTES);

    // XB/EB staging overlays Opart (consumed by gemm_all before flash writes it)
    short* XBhi = (short*)(ws + OPART_OFF);
    short* XBlo = (short*)(ws + OPART_OFF + 4718592);
    short* EBhi = (short*)(ws + OPART_OFF + 2 * 4718592);
    short* EBlo = (short*)(ws + OPART_OFF + 3 * 4718592);

    prep<<<dim3(1152, 2), dim3(256), 0, stream>>>(x, xe, XBhi, XBlo, EBhi, EBlo);
    wprep<<<dim3(40), dim3(256), 0, stream>>>(qw, kw, vw, WAhi, WAlo);
    gemm_all<<<dim3(144, 5), dim3(256), 0, stream>>>(
        XBhi, XBlo, EBhi, EBlo, WAhi, WAlo, qb, kb, hp, wp, vb, Qhi, Qlo, KP2, VF);
    flash<<<dim3(144 * nparts), dim3(256), 0, stream>>>(
        Qhi, Qlo, KP2, VF, Opart, Lpart, nparts - 1, mshift, NN / nparts);
    combine<<<dim3(2304), dim3(256), 0, stream>>>(Opart, Lpart, gm, x, (float*)d_out, nparts);
}